// Round 5
// baseline (139.463 us; speedup 1.0000x reference)
//
#include <hip/hip_runtime.h>

typedef __bf16 bf16;
typedef bf16 bf16x8 __attribute__((ext_vector_type(8)));
typedef bf16 bf16x4 __attribute__((ext_vector_type(4)));
typedef float f32x4 __attribute__((ext_vector_type(4)));

#define EPS 1e-5f
#define SLOPE 0.01f

// async global->LDS, 16B/lane. Invariant: lds ptr == wave-uniform base + lane*16B.
__device__ __forceinline__ void gld_lds16(const bf16* g, bf16* l) {
    __builtin_amdgcn_global_load_lds(
        (const __attribute__((address_space(1))) unsigned int*)g,
        (__attribute__((address_space(3))) unsigned int*)l, 16, 0, 0);
}

// ---------- prep: xT[b][l][c], xB[b][c][l], Wk/Wv/Wo bf16, WqT[h][c][e] ------
__global__ __launch_bounds__(256) void prep_kernel(
    const float* __restrict__ x,
    const float* __restrict__ Wq, const float* __restrict__ Wk,
    const float* __restrict__ Wv, const float* __restrict__ Wo,
    bf16* __restrict__ xT, bf16* __restrict__ xB,
    bf16* __restrict__ WkB, bf16* __restrict__ WvB,
    bf16* __restrict__ WoB, bf16* __restrict__ WqT)
{
    __shared__ float tile[64][65];
    const int id = blockIdx.x;
    const int t = threadIdx.x;
    if (id < 1024) {
        const int lt = id & 15, ct = (id >> 4) & 3, b = id >> 6;
        {
            const int cl = t >> 2;            // c within tile
            const int l4 = (t & 3) << 4;      // l within tile (16-chunks)
            const float* src = x + (size_t)(b * 256 + ct * 64 + cl) * 1024 + lt * 64 + l4;
            float4 v0 = ((const float4*)src)[0];
            float4 v1 = ((const float4*)src)[1];
            float4 v2 = ((const float4*)src)[2];
            float4 v3 = ((const float4*)src)[3];
            bf16x8 r0, r1;
            r0[0]=(bf16)v0.x; r0[1]=(bf16)v0.y; r0[2]=(bf16)v0.z; r0[3]=(bf16)v0.w;
            r0[4]=(bf16)v1.x; r0[5]=(bf16)v1.y; r0[6]=(bf16)v1.z; r0[7]=(bf16)v1.w;
            r1[0]=(bf16)v2.x; r1[1]=(bf16)v2.y; r1[2]=(bf16)v2.z; r1[3]=(bf16)v2.w;
            r1[4]=(bf16)v3.x; r1[5]=(bf16)v3.y; r1[6]=(bf16)v3.z; r1[7]=(bf16)v3.w;
            bf16* xbd = xB + (size_t)(b * 256 + ct * 64 + cl) * 1024 + lt * 64 + l4;
            *(bf16x8*)xbd = r0;
            *(bf16x8*)(xbd + 8) = r1;
            float* tr = &tile[cl][l4];
            tr[0]=v0.x; tr[1]=v0.y; tr[2]=v0.z; tr[3]=v0.w;
            tr[4]=v1.x; tr[5]=v1.y; tr[6]=v1.z; tr[7]=v1.w;
            tr[8]=v2.x; tr[9]=v2.y; tr[10]=v2.z; tr[11]=v2.w;
            tr[12]=v3.x; tr[13]=v3.y; tr[14]=v3.z; tr[15]=v3.w;
        }
        __syncthreads();
        {
            const int lw = t >> 2;            // l within tile
            const int ec = (t & 3) << 4;      // c within tile
            bf16x8 o0, o1;
            #pragma unroll
            for (int ii = 0; ii < 8; ++ii) {
                o0[ii] = (bf16)tile[ec + ii][lw];
                o1[ii] = (bf16)tile[ec + 8 + ii][lw];
            }
            bf16* dst = xT + (size_t)(b * 1024 + lt * 64 + lw) * 256 + ct * 64 + ec;
            *(bf16x8*)dst = o0;
            *(bf16x8*)(dst + 8) = o1;
        }
    } else if (id < 1408) {
        const int i = (id - 1024) * 1024 + t * 4;    // [0, 393216)
        const float* src; bf16* dst;
        if (i < 131072)      { src = Wk + i;            dst = WkB + i; }
        else if (i < 262144) { src = Wv + (i - 131072); dst = WvB + (i - 131072); }
        else                 { src = Wo + (i - 262144); dst = WoB + (i - 262144); }
        float4 v = *(const float4*)src;
        bf16x4 o;
        o[0]=(bf16)v.x; o[1]=(bf16)v.y; o[2]=(bf16)v.z; o[3]=(bf16)v.w;
        *(bf16x4*)dst = o;
    } else {
        // per-head transpose: WqT[h][c][e] = Wq[h*64+e][c]
        const int id2 = id - 1408;            // 0..31
        const int h = id2 >> 2, ct = id2 & 3;
        {
            const int e  = t >> 2;
            const int c4 = (t & 3) << 4;
            const float* src = Wq + (size_t)(h * 64 + e) * 256 + ct * 64 + c4;
            float4 v0 = ((const float4*)src)[0];
            float4 v1 = ((const float4*)src)[1];
            float4 v2 = ((const float4*)src)[2];
            float4 v3 = ((const float4*)src)[3];
            float* tr = &tile[e][c4];
            tr[0]=v0.x; tr[1]=v0.y; tr[2]=v0.z; tr[3]=v0.w;
            tr[4]=v1.x; tr[5]=v1.y; tr[6]=v1.z; tr[7]=v1.w;
            tr[8]=v2.x; tr[9]=v2.y; tr[10]=v2.z; tr[11]=v2.w;
            tr[12]=v3.x; tr[13]=v3.y; tr[14]=v3.z; tr[15]=v3.w;
        }
        __syncthreads();
        {
            const int c  = t >> 2;
            const int e4 = (t & 3) << 4;
            bf16x8 o0, o1;
            #pragma unroll
            for (int ii = 0; ii < 8; ++ii) {
                o0[ii] = (bf16)tile[e4 + ii][c];
                o1[ii] = (bf16)tile[e4 + 8 + ii][c];
            }
            bf16* dst = WqT + (size_t)h * 16384 + (size_t)(ct * 64 + c) * 64 + e4;
            *(bf16x8*)dst = o0;
            *(bf16x8*)(dst + 8) = o1;
        }
    }
}

// ------- 128x128-tile MFMA GEMM, B^T form (used for the Gram matrix) ---------
template<int KDIM, typename OutT>
__global__ __launch_bounds__(256) void gemm128_bt(
    const bf16* __restrict__ A, const bf16* __restrict__ Bt, OutT* __restrict__ C,
    long long sA, long long sBt, long long sC, int ldC)
{
    __shared__ bf16 As[128 * 32];
    __shared__ bf16 Bs[128 * 32];
    const int z = blockIdx.z;
    A  += (size_t)z * sA;
    Bt += (size_t)z * sBt;
    C  += (size_t)z * sC;
    const int m0 = blockIdx.x * 128;
    const int n0 = blockIdx.y * 128;
    const int t = threadIdx.x, w = t >> 6, l = t & 63;
    const int srow = w * 16 + (l >> 2);
    const int ske  = (l & 3) * 8;
    const bf16* ga = A  + (size_t)(m0 + srow) * KDIM + ske;
    const bf16* gb = Bt + (size_t)(n0 + srow) * KDIM + ske;
    bf16* la = As + srow * 32 + ske;
    bf16* lb = Bs + srow * 32 + ske;
    const int lm = l & 15, lq = l >> 4;
    const int wm = (w & 1) * 64, wn = (w >> 1) * 64;

    f32x4 acc[4][4] = {};
    for (int kt = 0; kt < KDIM / 32; ++kt) {
        const int k0 = kt * 32;
        gld_lds16(ga + k0, la);
        gld_lds16(ga + k0 + (size_t)64 * KDIM, la + 64 * 32);
        gld_lds16(gb + k0, lb);
        gld_lds16(gb + k0 + (size_t)64 * KDIM, lb + 64 * 32);
        __syncthreads();
        bf16x8 af[4], bfr[4];
        #pragma unroll
        for (int i = 0; i < 4; ++i)
            af[i] = *(const bf16x8*)(As + (wm + i * 16 + lm) * 32 + lq * 8);
        #pragma unroll
        for (int j = 0; j < 4; ++j)
            bfr[j] = *(const bf16x8*)(Bs + (wn + j * 16 + lm) * 32 + lq * 8);
        #pragma unroll
        for (int i = 0; i < 4; ++i)
            #pragma unroll
            for (int j = 0; j < 4; ++j)
                acc[i][j] = __builtin_amdgcn_mfma_f32_16x16x32_bf16(af[i], bfr[j], acc[i][j], 0, 0, 0);
        __syncthreads();
    }
    #pragma unroll
    for (int i = 0; i < 4; ++i)
        #pragma unroll
        for (int j = 0; j < 4; ++j) {
            const int row = m0 + wm + i * 16 + lq * 4;
            const int col = n0 + wn + j * 16 + lm;
            OutT* cp = C + (size_t)row * ldC + col;
            #pragma unroll
            for (int r = 0; r < 4; ++r)
                cp[(size_t)r * ldC] = (OutT)acc[i][j][r];
        }
}

// ---- per-(b,h): S=Wv_h G, T=S Wk_h^T/64, WmT_h[c][d]=sum_e WqT[c,e]T[d,e] ---
__global__ __launch_bounds__(256) void chain_kernel(
    const bf16* __restrict__ G, const bf16* __restrict__ WvB,
    const bf16* __restrict__ WkB, const bf16* __restrict__ WqT,
    bf16* __restrict__ WmT)
{
    __shared__ __align__(16) bf16 bufA[64 * 256];   // Wv_h -> WqT_h
    __shared__ __align__(16) bf16 bufB[256 * 64];   // G chunk -> Wk_h
    __shared__ __align__(16) bf16 Ss[64 * 256];
    __shared__ __align__(16) bf16 Tb[64 * 64];

    const int bh = blockIdx.x;
    const int b = bh >> 3, h = bh & 7;
    const int t = threadIdx.x, w = t >> 6, l = t & 63;
    const int lm = l & 15, lq = l >> 4;

    // ---- phase S: S[d,c'] = sum_ci Wv_h[d,ci] G[c',ci], M=64 N=256 K=256 ----
    // stage Wv_h [64][256], 32 segs/row, low-3 seg swizzle
    #pragma unroll
    for (int it = 0; it < 8; ++it) {
        const int slot = it * 256 + t;
        const int d = slot >> 5, seg = slot & 31;
        const int kq = (seg & 24) | ((seg & 7) ^ (d & 7));
        gld_lds16(WvB + (size_t)(h * 64 + d) * 256 + kq * 8, bufA + slot * 8);
    }
    f32x4 accS[4][4] = {};
    for (int ck = 0; ck < 4; ++ck) {
        // stage G chunk [256 c'][64 ci]
        #pragma unroll
        for (int it = 0; it < 8; ++it) {
            const int slot = it * 256 + t;
            const int cp = slot >> 3, seg = slot & 7;
            const int kq = seg ^ (cp & 7);
            gld_lds16(G + (size_t)b * 65536 + (size_t)cp * 256 + ck * 64 + kq * 8,
                      bufB + slot * 8);
        }
        __syncthreads();
        #pragma unroll
        for (int kt = 0; kt < 2; ++kt) {
            bf16x8 af[4], bfr[4];
            #pragma unroll
            for (int mf = 0; mf < 4; ++mf) {
                const int m = mf * 16 + lm;
                const int kqg = ck * 8 + kt * 4 + lq;   // 0..31
                const int seg = (kqg & 24) | ((kqg & 7) ^ (m & 7));
                af[mf] = *(const bf16x8*)(bufA + m * 256 + seg * 8);
            }
            #pragma unroll
            for (int nf = 0; nf < 4; ++nf) {
                const int n = w * 64 + nf * 16 + lm;
                const int kq = kt * 4 + lq;             // 0..7 within chunk
                const int seg = kq ^ (n & 7);
                bfr[nf] = *(const bf16x8*)(bufB + n * 64 + seg * 8);
            }
            #pragma unroll
            for (int mf = 0; mf < 4; ++mf)
                #pragma unroll
                for (int nf = 0; nf < 4; ++nf)
                    accS[mf][nf] = __builtin_amdgcn_mfma_f32_16x16x32_bf16(
                        af[mf], bfr[nf], accS[mf][nf], 0, 0, 0);
        }
        __syncthreads();
    }
    // write S to Ss [64][256] with swizzle
    #pragma unroll
    for (int mf = 0; mf < 4; ++mf)
        #pragma unroll
        for (int nf = 0; nf < 4; ++nf)
            #pragma unroll
            for (int r = 0; r < 4; ++r) {
                const int d = mf * 16 + lq * 4 + r;
                const int cp = w * 64 + nf * 16 + lm;
                const int s32 = cp >> 3;
                const int s = (s32 & 24) | ((s32 & 7) ^ (d & 7));
                Ss[d * 256 + s * 8 + (cp & 7)] = (bf16)accS[mf][nf][r];
            }
    // stage Wk_h into bufB (G chunks consumed)
    #pragma unroll
    for (int it = 0; it < 8; ++it) {
        const int slot = it * 256 + t;
        const int e = slot >> 5, seg = slot & 31;
        const int kq = (seg & 24) | ((seg & 7) ^ (e & 7));
        gld_lds16(WkB + (size_t)(h * 64 + e) * 256 + kq * 8, bufB + slot * 8);
    }
    __syncthreads();

    // ---- phase T: T[d,e] = (1/64) sum_c' S[d,c'] Wk[e,c'], 64x64 K=256 ------
    const int mh = (w & 1) * 32, nh = (w >> 1) * 32;
    f32x4 accT[2][2] = {};
    #pragma unroll
    for (int kt = 0; kt < 8; ++kt) {
        bf16x8 af[2], bfr[2];
        #pragma unroll
        for (int mf = 0; mf < 2; ++mf) {
            const int m = mh + mf * 16 + lm;
            const int kqg = kt * 4 + lq;
            const int seg = (kqg & 24) | ((kqg & 7) ^ (m & 7));
            af[mf] = *(const bf16x8*)(Ss + m * 256 + seg * 8);
        }
        #pragma unroll
        for (int nf = 0; nf < 2; ++nf) {
            const int n = nh + nf * 16 + lm;
            const int kqg = kt * 4 + lq;
            const int seg = (kqg & 24) | ((kqg & 7) ^ (n & 7));
            bfr[nf] = *(const bf16x8*)(bufB + n * 256 + seg * 8);
        }
        #pragma unroll
        for (int mf = 0; mf < 2; ++mf)
            #pragma unroll
            for (int nf = 0; nf < 2; ++nf)
                accT[mf][nf] = __builtin_amdgcn_mfma_f32_16x16x32_bf16(
                    af[mf], bfr[nf], accT[mf][nf], 0, 0, 0);
    }
    __syncthreads();   // Ss/bufA rewrites below need all reads done
    // write T (scaled) to Tb [64][64] swizzled
    #pragma unroll
    for (int mf = 0; mf < 2; ++mf)
        #pragma unroll
        for (int nf = 0; nf < 2; ++nf)
            #pragma unroll
            for (int r = 0; r < 4; ++r) {
                const int d = mh + mf * 16 + lq * 4 + r;
                const int e = nh + nf * 16 + lm;
                const int seg = (e >> 3) ^ (d & 7);
                Tb[d * 64 + seg * 8 + (e & 7)] = (bf16)(accT[mf][nf][r] * 0.015625f);
            }
    // stage WqT_h [256][64] into bufA
    #pragma unroll
    for (int it = 0; it < 8; ++it) {
        const int slot = it * 256 + t;
        const int c = slot >> 3, seg = slot & 7;
        const int kq = seg ^ (c & 7);
        gld_lds16(WqT + (size_t)h * 16384 + (size_t)c * 64 + kq * 8, bufA + slot * 8);
    }
    __syncthreads();

    // ---- phase M: WmT[c,d] = sum_e WqT[c,e] T[d,e], M=256 N=64 K=64 ---------
    f32x4 accM[4][4] = {};
    #pragma unroll
    for (int kt = 0; kt < 2; ++kt) {
        const int kq = kt * 4 + lq;
        bf16x8 bfr[4];
        #pragma unroll
        for (int nf = 0; nf < 4; ++nf) {
            const int n = nf * 16 + lm;
            bfr[nf] = *(const bf16x8*)(Tb + n * 64 + (kq ^ (n & 7)) * 8);
        }
        #pragma unroll
        for (int mf = 0; mf < 4; ++mf) {
            const int m = w * 64 + mf * 16 + lm;
            bf16x8 a = *(const bf16x8*)(bufA + m * 64 + (kq ^ (m & 7)) * 8);
            #pragma unroll
            for (int nf = 0; nf < 4; ++nf)
                accM[mf][nf] = __builtin_amdgcn_mfma_f32_16x16x32_bf16(
                    a, bfr[nf], accM[mf][nf], 0, 0, 0);
        }
    }
    bf16* Wg = WmT + (size_t)b * 131072 + h * 64;
    #pragma unroll
    for (int mf = 0; mf < 4; ++mf)
        #pragma unroll
        for (int nf = 0; nf < 4; ++nf)
            #pragma unroll
            for (int r = 0; r < 4; ++r) {
                const int c = w * 64 + mf * 16 + lq * 4 + r;
                const int d = nf * 16 + lm;
                Wg[(size_t)c * 512 + d] = (bf16)accM[mf][nf][r];
            }
}

// ---- fused: Wt tile = Wo WmT^T (16 rows), o = Wt x, InstanceNorm+res+lrelu --
// grid: 256 blocks = (b 0..15) x (ct 0..15); block owns rows c0=ct*16..+15.
__global__ __launch_bounds__(256) void outnorm_kernel(
    const bf16* __restrict__ WoB, const bf16* __restrict__ WmT,
    const bf16* __restrict__ xT, const bf16* __restrict__ xB,
    const float* __restrict__ gamma, float* __restrict__ y)
{
    __shared__ __align__(16) bf16 chunkBuf[32768];  // 64KB: Bt chunks / otile
    __shared__ __align__(16) bf16 WoS[16 * 512];    // 16KB
    __shared__ __align__(16) bf16 WtS[16 * 256];    // 8KB
    __shared__ float redS[4][16], redQ[4][16], bmu[16], binv[16];

    const int b = blockIdx.x >> 4, ct = blockIdx.x & 15;
    const int c0 = ct * 16;
    const int t = threadIdx.x, w = t >> 6, l = t & 63;
    const int lm = l & 15, lq = l >> 4;

    // ---- phase 1: WtS[co,ci] = sum_hd Wo[c0+co,hd] WmT[b][ci][hd], K=512 ----
    #pragma unroll
    for (int it = 0; it < 4; ++it) {           // stage Wo tile [16][512]
        const int slot = it * 256 + t;
        const int co = slot >> 6, seg = slot & 63;
        const int kq = (seg & 56) | ((seg & 7) ^ (co & 7));
        gld_lds16(WoB + (size_t)(c0 + co) * 512 + kq * 8, WoS + slot * 8);
    }
    f32x4 acc1[4] = {};
    for (int ck = 0; ck < 8; ++ck) {
        const int k0 = ck * 64;
        #pragma unroll
        for (int it = 0; it < 8; ++it) {       // stage WmT chunk [256 ci][64]
            const int slot = it * 256 + t;
            const int ci = slot >> 3, seg = slot & 7;
            const int kq = seg ^ (ci & 7);
            gld_lds16(WmT + (size_t)b * 131072 + (size_t)ci * 512 + k0 + kq * 8,
                      chunkBuf + slot * 8);
        }
        __syncthreads();
        #pragma unroll
        for (int kt = 0; kt < 2; ++kt) {
            const int kqg = ck * 8 + kt * 4 + lq;       // 0..63
            const int sa = (kqg & 56) | ((kqg & 7) ^ (lm & 7));
            bf16x8 a = *(const bf16x8*)(WoS + lm * 512 + sa * 8);
            #pragma unroll
            for (int nf = 0; nf < 4; ++nf) {
                const int n = w * 64 + nf * 16 + lm;
                const int kq = kt * 4 + lq;
                bf16x8 bb = *(const bf16x8*)(chunkBuf + n * 64 + (kq ^ (n & 7)) * 8);
                acc1[nf] = __builtin_amdgcn_mfma_f32_16x16x32_bf16(a, bb, acc1[nf], 0, 0, 0);
            }
        }
        __syncthreads();
    }
    #pragma unroll
    for (int nf = 0; nf < 4; ++nf)             // write WtS [16 co][256 ci]
        #pragma unroll
        for (int r = 0; r < 4; ++r) {
            const int co = lq * 4 + r;
            const int ci = w * 64 + nf * 16 + lm;
            const int s32 = ci >> 3;
            const int s = (s32 & 24) | ((s32 & 7) ^ (co & 7));
            WtS[co * 256 + s * 8 + (ci & 7)] = (bf16)acc1[nf][r];
        }
    __syncthreads();

    // ---- phase 2: o[co, l] = sum_ci WtS[co,ci] xT[b][l][ci], N=1024 K=256 ---
    f32x4 acc2[16] = {};
    for (int ck = 0; ck < 8; ++ck) {
        const int k0 = ck * 32;
        #pragma unroll
        for (int it = 0; it < 16; ++it) {      // stage x chunk [1024 l][32 ci]
            const int slot = it * 256 + t;
            const int ln = slot >> 2, seg = slot & 3;
            const int kq = seg ^ (ln & 3);
            gld_lds16(xT + (size_t)b * 262144 + (size_t)ln * 256 + k0 + kq * 8,
                      chunkBuf + slot * 8);
        }
        __syncthreads();
        const int kqg = ck * 4 + lq;           // 0..31
        const int sa = (kqg & 24) | ((kqg & 7) ^ (lm & 7));
        bf16x8 a = *(const bf16x8*)(WtS + lm * 256 + sa * 8);
        #pragma unroll
        for (int j = 0; j < 16; ++j) {
            const int n = w * 256 + j * 16 + lm;
            bf16x8 bb = *(const bf16x8*)(chunkBuf + n * 32 + ((lq ^ (n & 3)) * 8));
            acc2[j] = __builtin_amdgcn_mfma_f32_16x16x32_bf16(a, bb, acc2[j], 0, 0, 0);
        }
        __syncthreads();
    }

    // ---- phase 3: InstanceNorm over L, gamma residual, LeakyReLU, store -----
    float s[4] = {}, q[4] = {};
    #pragma unroll
    for (int j = 0; j < 16; ++j)
        #pragma unroll
        for (int r = 0; r < 4; ++r) {
            const float v = acc2[j][r];
            s[r] += v; q[r] += v * v;
        }
    #pragma unroll
    for (int off = 1; off < 16; off <<= 1)
        #pragma unroll
        for (int r = 0; r < 4; ++r) {
            s[r] += __shfl_xor(s[r], off);
            q[r] += __shfl_xor(q[r], off);
        }
    if (lm == 0)
        #pragma unroll
        for (int r = 0; r < 4; ++r) {
            redS[w][lq * 4 + r] = s[r];
            redQ[w][lq * 4 + r] = q[r];
        }
    __syncthreads();
    if (t < 16) {
        float S = redS[0][t] + redS[1][t] + redS[2][t] + redS[3][t];
        float Q = redQ[0][t] + redQ[1][t] + redQ[2][t] + redQ[3][t];
        const float mu = S * (1.0f / 1024.0f);
        const float var = Q * (1.0f / 1024.0f) - mu * mu;
        bmu[t] = mu;
        binv[t] = rsqrtf(var + EPS);
    }
    // write raw o into otile (reuse chunkBuf), rows padded to 1032
    bf16* otile = chunkBuf;
    #pragma unroll
    for (int j = 0; j < 16; ++j)
        #pragma unroll
        for (int r = 0; r < 4; ++r)
            otile[(lq * 4 + r) * 1032 + w * 256 + j * 16 + lm] = (bf16)acc2[j][r];
    __syncthreads();

    const float g = gamma[0];
    const int qd = t >> 6, l64 = t & 63;
    #pragma unroll
    for (int i = 0; i < 4; ++i) {
        const int c = qd * 4 + i;
        const float mu = bmu[c], inv = binv[c];
        bf16x8 o0 = *(const bf16x8*)(otile + c * 1032 + l64 * 16);
        bf16x8 o1 = *(const bf16x8*)(otile + c * 1032 + l64 * 16 + 8);
        const bf16* xr = xB + (size_t)(b * 256 + c0 + c) * 1024 + l64 * 16;
        bf16x8 x0 = *(const bf16x8*)xr;
        bf16x8 x1 = *(const bf16x8*)(xr + 8);
        float* yp = y + (size_t)(b * 256 + c0 + c) * 1024 + l64 * 16;
        float4 out[4];
        #pragma unroll
        for (int kk = 0; kk < 8; ++kk) {
            float v0 = ((float)o0[kk] - mu) * inv * g + (float)x0[kk];
            float v1 = ((float)o1[kk] - mu) * inv * g + (float)x1[kk];
            v0 = v0 >= 0.f ? v0 : SLOPE * v0;
            v1 = v1 >= 0.f ? v1 : SLOPE * v1;
            ((float*)out)[kk] = v0;
            ((float*)out)[8 + kk] = v1;
        }
        ((float4*)yp)[0] = out[0];
        ((float4*)yp)[1] = out[1];
        ((float4*)yp)[2] = out[2];
        ((float4*)yp)[3] = out[3];
    }
}

extern "C" void kernel_launch(void* const* d_in, const int* in_sizes, int n_in,
                              void* d_out, int out_size, void* d_ws, size_t ws_size,
                              hipStream_t stream) {
    const float* x     = (const float*)d_in[0];
    const float* Wq    = (const float*)d_in[1];
    const float* Wk    = (const float*)d_in[2];
    const float* Wv    = (const float*)d_in[3];
    const float* Wo    = (const float*)d_in[4];
    const float* gamma = (const float*)d_in[5];
    float* y = (float*)d_out;

    char* wsb = (char*)d_ws;
    bf16* xT  = (bf16*)(wsb);                   //  8,388,608
    bf16* xB  = (bf16*)(wsb +  8388608);        //  8,388,608
    bf16* WkB = (bf16*)(wsb + 16777216);        //    262,144
    bf16* WvB = (bf16*)(wsb + 17039360);        //    262,144
    bf16* WoB = (bf16*)(wsb + 17301504);        //    262,144
    bf16* WqT = (bf16*)(wsb + 17563648);        //    262,144
    bf16* G   = (bf16*)(wsb + 17825792);        //  2,097,152
    bf16* WmT = (bf16*)(wsb + 19922944);        //  4,194,304  (end 24,117,248)

    prep_kernel<<<dim3(1440), 256, 0, stream>>>(x, Wq, Wk, Wv, Wo, xT, xB, WkB, WvB, WoB, WqT);

    // G[b] = xB[b] (x) xB[b]^T : [256,256], K=1024 (symmetric Gram)
    gemm128_bt<1024, bf16><<<dim3(2, 2, 16), 256, 0, stream>>>(
        xB, xB, G, 262144LL, 262144LL, 65536LL, 256);

    // per (b,h): S, T, WmT
    chain_kernel<<<dim3(128), 256, 0, stream>>>(G, WvB, WkB, WqT, WmT);

    // per (b, 16-row tile): Wt rows, o rows, norm + residual + LeakyReLU
    outnorm_kernel<<<dim3(256), 256, 0, stream>>>(WoB, WmT, xT, xB, gamma, y);
}